// Round 6
// baseline (1903.774 us; speedup 1.0000x reference)
//
#include <hip/hip_runtime.h>
#include <hip/hip_bf16.h>

#define D 128

typedef float f32x4  __attribute__((ext_vector_type(4)));
typedef __attribute__((ext_vector_type(8))) __bf16 bh8;

__device__ inline float bf2f(unsigned short u) {
    union { unsigned int i; float f; } x; x.i = ((unsigned int)u) << 16; return x.f;
}
__device__ inline unsigned short f2bf(float f) {
    union { float f; unsigned int i; } x; x.f = f;
    return (unsigned short)((x.i + 0x7fffu + ((x.i >> 16) & 1u)) >> 16);
}
__device__ inline void acc2(unsigned int u, float& a, float& b) {
    union { unsigned int i; float f; } lo, hi;
    lo.i = u << 16; hi.i = u & 0xffff0000u;
    a += lo.f; b += hi.f;
}

// ---------------- CSR build ----------------
__global__ void k_hist(const int* __restrict__ edges, int E, int* __restrict__ deg) {
    int e = blockIdx.x * blockDim.x + threadIdx.x;
    if (e < E) {
        atomicAdd(&deg[edges[2 * e]], 1);
        atomicAdd(&deg[edges[2 * e + 1]], 1);
    }
}

__global__ void k_scan1(const int* __restrict__ deg, int n,
                        int* __restrict__ incl, int* __restrict__ bsum) {
    __shared__ int lds[1024];
    int t = threadIdx.x;
    int i = blockIdx.x * 1024 + t;
    int v = (i < n) ? deg[i] : 0;
    int cur = v;
    lds[t] = cur;
    __syncthreads();
    for (int off = 1; off < 1024; off <<= 1) {
        int add = (t >= off) ? lds[t - off] : 0;
        __syncthreads();
        cur += add;
        lds[t] = cur;
        __syncthreads();
    }
    if (i < n) incl[i] = cur;
    if (t == 1023) bsum[blockIdx.x] = cur;
}

__global__ void k_scan2(int* __restrict__ bsum, int nb) {
    __shared__ int lds[128];
    int t = threadIdx.x;
    int v = (t < nb) ? bsum[t] : 0;
    int cur = v;
    lds[t] = cur;
    __syncthreads();
    for (int off = 1; off < 128; off <<= 1) {
        int add = (t >= off) ? lds[t - off] : 0;
        __syncthreads();
        cur += add;
        lds[t] = cur;
        __syncthreads();
    }
    if (t < nb) bsum[t] = cur - v;  // exclusive
}

__global__ void k_scan3(const int* __restrict__ incl, const int* __restrict__ deg,
                        const int* __restrict__ bsum, int n, int twoE,
                        int* __restrict__ rowstart, int* __restrict__ cursor) {
    int i = blockIdx.x * blockDim.x + threadIdx.x;
    if (i < n) {
        int r = incl[i] - deg[i] + bsum[i >> 10];
        rowstart[i] = r;
        cursor[i] = r;
    }
    if (i == 0) rowstart[n] = twoE;
}

__global__ void k_fill(const int* __restrict__ edges, int E,
                       int* __restrict__ cursor, int* __restrict__ adj) {
    int e = blockIdx.x * blockDim.x + threadIdx.x;
    if (e < E) {
        int a = edges[2 * e], b = edges[2 * e + 1];
        adj[atomicAdd(&cursor[a], 1)] = b;
        adj[atomicAdd(&cursor[b], 1)] = a;
    }
}

// ---------------- weight prep: bf16, BK=64-chunked layout ----------------
// wb[l][c][o][kk]: K = c*64+kk; m = K>>7 (0:W0,1:W1); k = K&127; val = Wm[o][k]
__global__ void k_wprep(const float* __restrict__ W0_1, const float* __restrict__ W1_1,
                        const float* __restrict__ W0_h, const float* __restrict__ W1_h,
                        unsigned short* __restrict__ wb) {
    int idx = blockIdx.x * 256 + threadIdx.x;
    if (idx >= 13 * 4 * 128 * 64) return;
    int kk = idx & 63;
    int o = (idx >> 6) & 127;
    int c = (idx >> 13) & 3;
    int l = idx >> 15;
    int K = c * 64 + kk;
    int m = K >> 7;
    int k = K & 127;
    const float* src = (l == 0) ? (m ? W1_1 : W0_1)
                                : ((m ? W1_h : W0_h) + (size_t)(l - 1) * 16384);
    wb[idx] = f2bf(src[o * 128 + k]);
}

// ---------------- fp32 -> bf16 convert ----------------
__global__ void k_cvt(const float* __restrict__ in, unsigned short* __restrict__ out, int n4) {
    int i = blockIdx.x * blockDim.x + threadIdx.x;
    if (i >= n4) return;
    f32x4 v = *(const f32x4*)&in[(size_t)i * 4];
    unsigned short u[4];
    #pragma unroll
    for (int j = 0; j < 4; ++j) u[j] = f2bf(v[j]);
    *(uint2*)&out[(size_t)i * 4] = *(uint2*)u;
}

// ---------------- bf16 add: c = a + b ----------------
__global__ void k_addb(const unsigned short* __restrict__ a, const unsigned short* __restrict__ b,
                       unsigned short* __restrict__ c, int n2) {
    int i = blockIdx.x * blockDim.x + threadIdx.x;
    if (i >= n2) return;
    unsigned int ua = ((const unsigned int*)a)[i];
    unsigned int ub = ((const unsigned int*)b)[i];
    union { unsigned int i; float f; } la, ha, lb, hb;
    la.i = ua << 16; ha.i = ua & 0xffff0000u;
    lb.i = ub << 16; hb.i = ub & 0xffff0000u;
    unsigned int out = ((unsigned int)f2bf(ha.f + hb.f) << 16) | f2bf(la.f + lb.f);
    ((unsigned int*)c)[i] = out;
}

// ---------------- standalone aggregation (final layer only) ----------------
__global__ __launch_bounds__(256) void k_agg(
    const unsigned short* __restrict__ x, const int* __restrict__ rowstart,
    const int* __restrict__ adj, unsigned short* __restrict__ s, int n) {
    int node = blockIdx.x * 4 + (threadIdx.x >> 6);
    int lane = threadIdx.x & 63;
    if (node >= n) return;
    int r0 = rowstart[node], r1 = rowstart[node + 1];
    float a[8], b[8];
    #pragma unroll
    for (int k = 0; k < 8; ++k) { a[k] = 0.f; b[k] = 0.f; }
    for (int p = r0; p < r1; p += 8) {
        int q = p + (lane & 7);
        int idx = (q < r1) ? adj[q] : 0;
        unsigned int u[8];
        #pragma unroll
        for (int k = 0; k < 8; ++k) {
            int j = __shfl(idx, k);
            u[k] = *(const unsigned int*)&x[(size_t)j * D + lane * 2];
        }
        #pragma unroll
        for (int k = 0; k < 8; ++k)
            if (p + k < r1) acc2(u[k], a[k], b[k]);
    }
    float f0 = ((a[0] + a[1]) + (a[2] + a[3])) + ((a[4] + a[5]) + (a[6] + a[7]));
    float f1 = ((b[0] + b[1]) + (b[2] + b[3])) + ((b[4] + b[5]) + (b[6] + b[7]));
    unsigned int out = ((unsigned int)f2bf(f1) << 16) | f2bf(f0);
    *(unsigned int*)&s[(size_t)node * D + lane * 2] = out;
}

// ---------------- FUSED layer: gather + dual-GEMM + bias + relu ----------------
// Block = 64 nodes, 256 threads = 4 waves (2x2 grid of 32x64 subtiles).
// A-tile (64 x 256, K = [x | gathered s]) resident in LDS for the whole kernel;
// s-half is gathered directly from x (no HBM round-trip). B streamed in 4 BK=64
// stages with register prefetch.
#define ASTR2 264
#define BSTR 72
#define OSTR 136
__global__ __launch_bounds__(256) void k_fused(
    const unsigned short* __restrict__ x,   // [n][128] bf16
    const int* __restrict__ rowstart, const int* __restrict__ adj,
    const unsigned short* __restrict__ wb,  // layer weights [4][128][64] bf16
    const float* __restrict__ b0, const float* __restrict__ b1,
    const int* __restrict__ deg,
    unsigned short* __restrict__ out,       // [n][128] bf16
    float* __restrict__ out32,              // optional fp32 copy (aux), may be null
    int n, int do_relu) {
    __shared__ __align__(16) unsigned short LDS[64 * ASTR2 + 128 * BSTR];  // 52224 B
    unsigned short* Alds = LDS;                   // 64 x ASTR2 (cols 0..255 = K)
    unsigned short* Blds = LDS + 64 * ASTR2;      // 128 x BSTR
    int t = threadIdx.x;
    int node0 = blockIdx.x * 64;
    int lane = t & 63;
    int wave = t >> 6;
    int wm = (wave & 1) * 32;
    int wn = (wave >> 1) * 64;
    int mlane = lane & 15;
    int quad = lane >> 4;

    // ---- (1) issue x-half staging loads (64 nodes x 128 k) ----
    int rowx = t >> 2;
    int segx = (t & 3) * 8;
    uint4 xr[4];
    {
        int g = node0 + rowx;
        #pragma unroll
        for (int p = 0; p < 4; ++p) {
            uint4 v = {0u, 0u, 0u, 0u};
            if (g < n) v = *(const uint4*)&x[(size_t)g * D + segx + p * 32];
            xr[p] = v;
        }
    }
    // ---- (2) issue B stage-0 loads ----
    uint4 br[4];
    #pragma unroll
    for (int p = 0; p < 4; ++p)
        br[p] = *(const uint4*)&wb[(size_t)(p * 256 + t) * 8];

    // ---- (3) gather s-half directly into LDS: wave w owns rows w*16..w*16+15 ----
    #pragma unroll 1
    for (int i = 0; i < 16; ++i) {
        int ndrow = wave * 16 + i;
        int node = node0 + ndrow;
        float f0 = 0.f, f1 = 0.f;
        if (node < n) {
            int r0 = rowstart[node], r1 = rowstart[node + 1];
            float a[8], b[8];
            #pragma unroll
            for (int k = 0; k < 8; ++k) { a[k] = 0.f; b[k] = 0.f; }
            for (int p = r0; p < r1; p += 8) {
                int q = p + (lane & 7);
                int idx = (q < r1) ? adj[q] : 0;
                unsigned int u[8];
                #pragma unroll
                for (int k = 0; k < 8; ++k) {
                    int j = __shfl(idx, k);
                    u[k] = *(const unsigned int*)&x[(size_t)j * D + lane * 2];
                }
                #pragma unroll
                for (int k = 0; k < 8; ++k)
                    if (p + k < r1) acc2(u[k], a[k], b[k]);
            }
            f0 = ((a[0] + a[1]) + (a[2] + a[3])) + ((a[4] + a[5]) + (a[6] + a[7]));
            f1 = ((b[0] + b[1]) + (b[2] + b[3])) + ((b[4] + b[5]) + (b[6] + b[7]));
        }
        unsigned int pk = ((unsigned int)f2bf(f1) << 16) | f2bf(f0);
        *(unsigned int*)&Alds[ndrow * ASTR2 + 128 + lane * 2] = pk;
    }

    // ---- (4) commit x-half + B stage-0 to LDS ----
    #pragma unroll
    for (int p = 0; p < 4; ++p)
        *(uint4*)&Alds[rowx * ASTR2 + segx + p * 32] = xr[p];
    #pragma unroll
    for (int p = 0; p < 4; ++p) {
        int c = p * 256 + t;
        *(uint4*)&Blds[(c >> 3) * BSTR + (c & 7) * 8] = br[p];
    }
    __syncthreads();

    // ---- (5) K-loop: 4 stages of BK=64 ----
    f32x4 acc[2][4];
    #pragma unroll
    for (int i = 0; i < 2; ++i)
        #pragma unroll
        for (int j = 0; j < 4; ++j) acc[i][j] = (f32x4){0.f, 0.f, 0.f, 0.f};

    for (int s = 0; s < 4; ++s) {
        if (s < 3) {
            #pragma unroll
            for (int p = 0; p < 4; ++p)
                br[p] = *(const uint4*)&wb[(size_t)(s + 1) * 8192 + (size_t)(p * 256 + t) * 8];
        }
        bh8 af[2][2], bf_[4][2];
        #pragma unroll
        for (int i = 0; i < 2; ++i)
            #pragma unroll
            for (int h = 0; h < 2; ++h)
                af[i][h] = *(const bh8*)&Alds[(wm + i * 16 + mlane) * ASTR2 + s * 64 + quad * 8 + h * 32];
        #pragma unroll
        for (int j = 0; j < 4; ++j)
            #pragma unroll
            for (int h = 0; h < 2; ++h)
                bf_[j][h] = *(const bh8*)&Blds[(wn + j * 16 + mlane) * BSTR + quad * 8 + h * 32];
        #pragma unroll
        for (int i = 0; i < 2; ++i)
            #pragma unroll
            for (int j = 0; j < 4; ++j) {
                acc[i][j] = __builtin_amdgcn_mfma_f32_16x16x32_bf16(af[i][0], bf_[j][0], acc[i][j], 0, 0, 0);
                acc[i][j] = __builtin_amdgcn_mfma_f32_16x16x32_bf16(af[i][1], bf_[j][1], acc[i][j], 0, 0, 0);
            }
        if (s < 3) {
            __syncthreads();   // all waves done reading Blds stage s
            #pragma unroll
            for (int p = 0; p < 4; ++p) {
                int c = p * 256 + t;
                *(uint4*)&Blds[(c >> 3) * BSTR + (c & 7) * 8] = br[p];
            }
            __syncthreads();
        }
    }

    // ---- (6) epilogue: bias + deg*b1 + relu -> LDS transpose -> coalesced stores ----
    __syncthreads();   // done with Alds; reuse as Olds
    #pragma unroll
    for (int i = 0; i < 2; ++i) {
        int mrow = wm + i * 16 + quad * 4;
        #pragma unroll
        for (int j = 0; j < 4; ++j) {
            int nn = wn + j * 16 + mlane;
            float b0v = b0[nn], b1v = b1[nn];
            #pragma unroll
            for (int r = 0; r < 4; ++r) {
                int g = node0 + mrow + r;
                float dg = (g < n) ? (float)deg[g] : 0.f;
                float val = acc[i][j][r] + b0v + dg * b1v;
                if (do_relu) val = fmaxf(val, 0.f);
                LDS[(mrow + r) * OSTR + nn] = f2bf(val);
            }
        }
    }
    __syncthreads();
    #pragma unroll
    for (int pass = 0; pass < 4; ++pass) {
        int row = pass * 16 + (t >> 4);
        int seg = (t & 15) * 8;
        int g = node0 + row;
        if (g < n)
            *(uint4*)&out[(size_t)g * D + seg] = *(const uint4*)&LDS[row * OSTR + seg];
    }
    if (out32) {
        #pragma unroll
        for (int pass = 0; pass < 8; ++pass) {
            int row = pass * 8 + (t >> 5);
            int seg = (t & 31) * 4;
            int g = node0 + row;
            if (g < n) {
                f32x4 v;
                #pragma unroll
                for (int j = 0; j < 4; ++j) v[j] = bf2f(LDS[row * OSTR + seg + j]);
                *(f32x4*)&out32[(size_t)g * D + seg] = v;
            }
        }
    }
}

// ---------------- last layer (D_out = 3, fp32 out, no relu) ----------------
__global__ void k_last(const unsigned short* __restrict__ z, const unsigned short* __restrict__ sz,
                       const float* __restrict__ W0, const float* __restrict__ b0,
                       const float* __restrict__ W1, const float* __restrict__ b1,
                       const int* __restrict__ deg, float* __restrict__ vert, int n) {
    int t = threadIdx.x;
    int lane = t & 63;
    int node = blockIdx.x * 4 + (t >> 6);
    if (node >= n) return;
    float z0 = bf2f(z[(size_t)node * D + lane]), z1 = bf2f(z[(size_t)node * D + 64 + lane]);
    float s0 = bf2f(sz[(size_t)node * D + lane]), s1 = bf2f(sz[(size_t)node * D + 64 + lane]);
    float dg = (float)deg[node];
    #pragma unroll
    for (int o = 0; o < 3; ++o) {
        float p = z0 * W0[o * D + lane] + z1 * W0[o * D + 64 + lane]
                + s0 * W1[o * D + lane] + s1 * W1[o * D + 64 + lane];
        for (int off = 32; off > 0; off >>= 1) p += __shfl_down(p, off);
        if (lane == 0) vert[(size_t)node * 3 + o] = p + b0[o] + dg * b1[o];
    }
}

extern "C" void kernel_launch(void* const* d_in, const int* in_sizes, int n_in,
                              void* d_out, int out_size, void* d_ws, size_t ws_size,
                              hipStream_t stream) {
    const float* features = (const float*)d_in[0];
    const int*   edges    = (const int*)d_in[1];
    const float* W0_1 = (const float*)d_in[2];
    const float* b0_1 = (const float*)d_in[3];
    const float* W1_1 = (const float*)d_in[4];
    const float* b1_1 = (const float*)d_in[5];
    const float* W0_h = (const float*)d_in[6];
    const float* b0_h = (const float*)d_in[7];
    const float* W1_h = (const float*)d_in[8];
    const float* b1_h = (const float*)d_in[9];
    const float* W0_l = (const float*)d_in[10];
    const float* b0_l = (const float*)d_in[11];
    const float* W1_l = (const float*)d_in[12];
    const float* b1_l = (const float*)d_in[13];

    const int N_ = 100000, E_ = 300000;
    float* vert = (float*)d_out;                    // N*3
    float* aux  = (float*)d_out + (size_t)N_ * 3;   // N*128 fp32

    char* w = (char*)d_ws;
    auto alloc = [&](size_t bytes) {
        char* p = w;
        w += (bytes + 255) & ~(size_t)255;
        return p;
    };
    unsigned short* wb    = (unsigned short*)alloc((size_t)13 * 32768 * 2);
    unsigned short* xf    = (unsigned short*)alloc((size_t)N_ * D * 2);
    unsigned short* resid = (unsigned short*)alloc((size_t)N_ * D * 2);
    unsigned short* xa    = (unsigned short*)alloc((size_t)N_ * D * 2);
    unsigned short* xb    = (unsigned short*)alloc((size_t)N_ * D * 2);
    unsigned short* sb    = (unsigned short*)alloc((size_t)N_ * D * 2);
    int* deg    = (int*)alloc((size_t)N_ * 4);
    int* incl   = (int*)alloc((size_t)N_ * 4);
    int* rowst  = (int*)alloc((size_t)(N_ + 1) * 4);
    int* cursor = (int*)alloc((size_t)N_ * 4);
    int* bsum   = (int*)alloc(128 * 4);
    int* adj    = (int*)alloc((size_t)2 * E_ * 4);

    // CSR build
    hipMemsetAsync(deg, 0, (size_t)N_ * 4, stream);
    k_hist<<<(E_ + 255) / 256, 256, 0, stream>>>(edges, E_, deg);
    int nb = (N_ + 1023) / 1024;   // 98
    k_scan1<<<nb, 1024, 0, stream>>>(deg, N_, incl, bsum);
    k_scan2<<<1, 128, 0, stream>>>(bsum, nb);
    k_scan3<<<(N_ + 255) / 256, 256, 0, stream>>>(incl, deg, bsum, N_, 2 * E_, rowst, cursor);
    k_fill<<<(E_ + 255) / 256, 256, 0, stream>>>(edges, E_, cursor, adj);

    // weight + feature conversion
    k_wprep<<<(13 * 4 * 128 * 64 + 255) / 256, 256, 0, stream>>>(W0_1, W1_1, W0_h, W1_h, wb);
    k_cvt<<<(N_ * D / 4 + 255) / 256, 256, 0, stream>>>(features, xf, N_ * D / 4);

    int gblocks = (N_ + 63) / 64;    // 1563
    int ablocks = (N_ + 3) / 4;

    // layer 1: xf -> resid (fused gather+gemm)
    k_fused<<<gblocks, 256, 0, stream>>>(xf, rowst, adj, wb, b0_1, b1_1, deg, resid, nullptr, N_, 1);

    // 12 hidden layers
    for (int h = 0; h < 12; ++h) {
        const unsigned short* in = (h == 0) ? resid : ((h & 1) ? xa : xb);
        unsigned short* outp = (h & 1) ? xb : xa;
        float* o32 = (h == 11) ? aux : nullptr;
        k_fused<<<gblocks, 256, 0, stream>>>(in, rowst, adj, wb + (size_t)(1 + h) * 32768,
                                             b0_h + h * 128, b1_h + h * 128, deg, outp, o32, N_, 1);
    }

    // last layer: z = resid + x12 (in xb); vertices = gconv(z), no relu
    k_addb<<<(N_ * D / 2 + 255) / 256, 256, 0, stream>>>(resid, xb, xa, N_ * D / 2);
    k_agg<<<ablocks, 256, 0, stream>>>(xa, rowst, adj, sb, N_);
    k_last<<<ablocks, 256, 0, stream>>>(xa, sb, W0_l, b0_l, W1_l, b1_l, deg, vert, N_);
}

// Round 7
// 1362.838 us; speedup vs baseline: 1.3969x; 1.3969x over previous
//
#include <hip/hip_runtime.h>
#include <hip/hip_bf16.h>

#define D 128

typedef float f32x4  __attribute__((ext_vector_type(4)));
typedef __attribute__((ext_vector_type(8))) __bf16 bh8;

__device__ inline float bf2f(unsigned short u) {
    union { unsigned int i; float f; } x; x.i = ((unsigned int)u) << 16; return x.f;
}
__device__ inline unsigned short f2bf(float f) {
    union { float f; unsigned int i; } x; x.f = f;
    return (unsigned short)((x.i + 0x7fffu + ((x.i >> 16) & 1u)) >> 16);
}
__device__ inline void acc2(unsigned int u, float& a, float& b) {
    union { unsigned int i; float f; } lo, hi;
    lo.i = u << 16; hi.i = u & 0xffff0000u;
    a += lo.f; b += hi.f;
}

// ---------------- CSR build ----------------
__global__ void k_hist(const int* __restrict__ edges, int E, int* __restrict__ deg) {
    int e = blockIdx.x * blockDim.x + threadIdx.x;
    if (e < E) {
        atomicAdd(&deg[edges[2 * e]], 1);
        atomicAdd(&deg[edges[2 * e + 1]], 1);
    }
}

__global__ void k_scan1(const int* __restrict__ deg, int n,
                        int* __restrict__ incl, int* __restrict__ bsum) {
    __shared__ int lds[1024];
    int t = threadIdx.x;
    int i = blockIdx.x * 1024 + t;
    int v = (i < n) ? deg[i] : 0;
    int cur = v;
    lds[t] = cur;
    __syncthreads();
    for (int off = 1; off < 1024; off <<= 1) {
        int add = (t >= off) ? lds[t - off] : 0;
        __syncthreads();
        cur += add;
        lds[t] = cur;
        __syncthreads();
    }
    if (i < n) incl[i] = cur;
    if (t == 1023) bsum[blockIdx.x] = cur;
}

__global__ void k_scan2(int* __restrict__ bsum, int nb) {
    __shared__ int lds[128];
    int t = threadIdx.x;
    int v = (t < nb) ? bsum[t] : 0;
    int cur = v;
    lds[t] = cur;
    __syncthreads();
    for (int off = 1; off < 128; off <<= 1) {
        int add = (t >= off) ? lds[t - off] : 0;
        __syncthreads();
        cur += add;
        lds[t] = cur;
        __syncthreads();
    }
    if (t < nb) bsum[t] = cur - v;  // exclusive
}

__global__ void k_scan3(const int* __restrict__ incl, const int* __restrict__ deg,
                        const int* __restrict__ bsum, int n, int twoE,
                        int* __restrict__ rowstart, int* __restrict__ cursor) {
    int i = blockIdx.x * blockDim.x + threadIdx.x;
    if (i < n) {
        int r = incl[i] - deg[i] + bsum[i >> 10];
        rowstart[i] = r;
        cursor[i] = r;
    }
    if (i == 0) rowstart[n] = twoE;
}

__global__ void k_fill(const int* __restrict__ edges, int E,
                       int* __restrict__ cursor, int* __restrict__ adj) {
    int e = blockIdx.x * blockDim.x + threadIdx.x;
    if (e < E) {
        int a = edges[2 * e], b = edges[2 * e + 1];
        adj[atomicAdd(&cursor[a], 1)] = b;
        adj[atomicAdd(&cursor[b], 1)] = a;
    }
}

// ---------------- weight prep: wb[l][m][o][k] = bf16(Wm[o][k]) ----------------
// Stage m of the K-loop uses exactly Wm (K 0..127 = W0 vs x, 128..255 = W1 vs s).
__global__ void k_wprep(const float* __restrict__ W0_1, const float* __restrict__ W1_1,
                        const float* __restrict__ W0_h, const float* __restrict__ W1_h,
                        unsigned short* __restrict__ wb) {
    int idx = blockIdx.x * 256 + threadIdx.x;
    if (idx >= 13 * 2 * 128 * 128) return;
    int k = idx & 127;
    int o = (idx >> 7) & 127;
    int m = (idx >> 14) & 1;
    int l = idx >> 15;
    const float* src = (l == 0) ? (m ? W1_1 : W0_1)
                                : ((m ? W1_h : W0_h) + (size_t)(l - 1) * 16384);
    wb[idx] = f2bf(src[o * 128 + k]);
}

// ---------------- fp32 -> bf16 convert ----------------
__global__ void k_cvt(const float* __restrict__ in, unsigned short* __restrict__ out, int n4) {
    int i = blockIdx.x * blockDim.x + threadIdx.x;
    if (i >= n4) return;
    f32x4 v = *(const f32x4*)&in[(size_t)i * 4];
    unsigned short u[4];
    #pragma unroll
    for (int j = 0; j < 4; ++j) u[j] = f2bf(v[j]);
    *(uint2*)&out[(size_t)i * 4] = *(uint2*)u;
}

// ---------------- bf16 add: c = a + b ----------------
__global__ void k_addb(const unsigned short* __restrict__ a, const unsigned short* __restrict__ b,
                       unsigned short* __restrict__ c, int n2) {
    int i = blockIdx.x * blockDim.x + threadIdx.x;
    if (i >= n2) return;
    unsigned int ua = ((const unsigned int*)a)[i];
    unsigned int ub = ((const unsigned int*)b)[i];
    union { unsigned int i; float f; } la, ha, lb, hb;
    la.i = ua << 16; ha.i = ua & 0xffff0000u;
    lb.i = ub << 16; hb.i = ub & 0xffff0000u;
    unsigned int out = ((unsigned int)f2bf(ha.f + hb.f) << 16) | f2bf(la.f + lb.f);
    ((unsigned int*)c)[i] = out;
}

// ---------------- neighbor aggregation ----------------
// 4 nodes per wave (16-lane groups, uint4 row loads) => 16 independent loads in flight.
__global__ __launch_bounds__(256) void k_agg(
    const unsigned short* __restrict__ x, const int* __restrict__ rowstart,
    const int* __restrict__ adj, unsigned short* __restrict__ s, int n) {
    int t = threadIdx.x;
    int glane = t & 15;
    int node = blockIdx.x * 16 + (t >> 4);
    if (node >= n) return;
    int r0 = rowstart[node], r1 = rowstart[node + 1];
    int base = t & 48;   // group base lane within the wave
    float a[8];
    #pragma unroll
    for (int j = 0; j < 8; ++j) a[j] = 0.f;
    for (int p = r0; p < r1; p += 4) {
        int q = p + (glane & 3);
        int idx = (q < r1) ? adj[q] : 0;
        uint4 u[4];
        #pragma unroll
        for (int k = 0; k < 4; ++k) {
            int j = __shfl(idx, base + k);
            u[k] = *(const uint4*)&x[(size_t)j * D + glane * 8];
        }
        #pragma unroll
        for (int k = 0; k < 4; ++k) {
            if (p + k < r1) {
                acc2(u[k].x, a[0], a[1]);
                acc2(u[k].y, a[2], a[3]);
                acc2(u[k].z, a[4], a[5]);
                acc2(u[k].w, a[6], a[7]);
            }
        }
    }
    unsigned int w[4];
    #pragma unroll
    for (int j = 0; j < 4; ++j)
        w[j] = ((unsigned int)f2bf(a[2 * j + 1]) << 16) | f2bf(a[2 * j]);
    *(uint4*)&s[(size_t)node * D + glane * 8] = *(const uint4*)w;
}

// ---------------- MFMA GEMM: out = act([x|s] @ [W0T;W1T] + b0 + deg*b1) ----------------
// 256 threads = 4 waves (2x2 of 32x64 subtiles); block = 64 nodes x 128 outs.
// K=256 in TWO BK=128 stages: stage 0 = x vs W0, stage 1 = s vs W1.
// Only 5 barriers per block (vs 17 in the 8-chunk version).
#define ASTR 136
#define OSTR 136
__global__ __launch_bounds__(256) void k_gemm(
    const unsigned short* __restrict__ x,   // [n][128] bf16
    const unsigned short* __restrict__ s,   // [n][128] bf16
    const unsigned short* __restrict__ wb,  // [2][128][128] bf16 (m, o, k)
    const float* __restrict__ b0, const float* __restrict__ b1,
    const int* __restrict__ deg,
    unsigned short* __restrict__ out,       // [n][128] bf16
    float* __restrict__ out32,              // optional fp32 copy (aux), may be null
    int n, int do_relu) {
    __shared__ __align__(16) unsigned short LDS[64 * ASTR + 128 * ASTR];  // 52224 B
    unsigned short* Alds = LDS;                // 64 x ASTR
    unsigned short* Blds = LDS + 64 * ASTR;    // 128 x ASTR
    int t = threadIdx.x;
    int node0 = blockIdx.x * 64;
    int lane = t & 63;
    int wave = t >> 6;
    int wm = (wave & 1) * 32;
    int wn = (wave >> 1) * 64;
    int mlane = lane & 15;
    int quad = lane >> 4;

    // A staging: row = t>>2 (64 rows), 4 threads/row x 64B; col in shorts
    int rowA = t >> 2;
    int colA = (t & 3) * 32;
    // B staging: row = t>>1 (128 rows), 2 threads/row x 128B
    int rowB = t >> 1;
    int colB = (t & 1) * 64;

    uint4 xa[4], wr[8];
    auto fetchA = [&](const unsigned short* __restrict__ src) {
        int g = node0 + rowA;
        #pragma unroll
        for (int p = 0; p < 4; ++p) {
            uint4 v = {0u, 0u, 0u, 0u};
            if (g < n) v = *(const uint4*)&src[(size_t)g * D + colA + p * 8];
            xa[p] = v;
        }
    };
    auto fetchB = [&](int m) {
        #pragma unroll
        for (int p = 0; p < 8; ++p)
            wr[p] = *(const uint4*)&wb[(size_t)m * 16384 + (size_t)rowB * 128 + colB + p * 8];
    };
    auto commitA = [&]() {
        #pragma unroll
        for (int p = 0; p < 4; ++p)
            *(uint4*)&Alds[rowA * ASTR + colA + p * 8] = xa[p];
    };
    auto commitB = [&]() {
        #pragma unroll
        for (int p = 0; p < 8; ++p)
            *(uint4*)&Blds[rowB * ASTR + colB + p * 8] = wr[p];
    };

    f32x4 acc[2][4];
    #pragma unroll
    for (int i = 0; i < 2; ++i)
        #pragma unroll
        for (int j = 0; j < 4; ++j) acc[i][j] = (f32x4){0.f, 0.f, 0.f, 0.f};

    // stage 0: x vs W0
    fetchA(x);
    fetchB(0);
    commitA();
    commitB();
    __syncthreads();
    fetchA(s);        // prefetch stage-1 A during stage-0 compute
    #pragma unroll
    for (int ks = 0; ks < 4; ++ks) {
        bh8 af[2], bf_[4];
        #pragma unroll
        for (int i = 0; i < 2; ++i)
            af[i] = *(const bh8*)&Alds[(wm + i * 16 + mlane) * ASTR + ks * 32 + quad * 8];
        #pragma unroll
        for (int j = 0; j < 4; ++j)
            bf_[j] = *(const bh8*)&Blds[(wn + j * 16 + mlane) * ASTR + ks * 32 + quad * 8];
        #pragma unroll
        for (int i = 0; i < 2; ++i)
            #pragma unroll
            for (int j = 0; j < 4; ++j)
                acc[i][j] = __builtin_amdgcn_mfma_f32_16x16x32_bf16(af[i], bf_[j], acc[i][j], 0, 0, 0);
    }
    fetchB(1);        // W1 is L2-resident; hides behind the A drain
    __syncthreads();  // everyone done reading stage-0 LDS
    commitA();
    commitB();
    __syncthreads();
    // stage 1: s vs W1
    #pragma unroll
    for (int ks = 0; ks < 4; ++ks) {
        bh8 af[2], bf_[4];
        #pragma unroll
        for (int i = 0; i < 2; ++i)
            af[i] = *(const bh8*)&Alds[(wm + i * 16 + mlane) * ASTR + ks * 32 + quad * 8];
        #pragma unroll
        for (int j = 0; j < 4; ++j)
            bf_[j] = *(const bh8*)&Blds[(wn + j * 16 + mlane) * ASTR + ks * 32 + quad * 8];
        #pragma unroll
        for (int i = 0; i < 2; ++i)
            #pragma unroll
            for (int j = 0; j < 4; ++j)
                acc[i][j] = __builtin_amdgcn_mfma_f32_16x16x32_bf16(af[i], bf_[j], acc[i][j], 0, 0, 0);
    }

    // ---- epilogue: bias + deg*b1 + relu -> LDS transpose -> coalesced stores ----
    __syncthreads();   // done with staging; reuse LDS as Olds
    #pragma unroll
    for (int i = 0; i < 2; ++i) {
        int mrow = wm + i * 16 + quad * 4;
        #pragma unroll
        for (int j = 0; j < 4; ++j) {
            int nn = wn + j * 16 + mlane;
            float b0v = b0[nn], b1v = b1[nn];
            #pragma unroll
            for (int r = 0; r < 4; ++r) {
                int g = node0 + mrow + r;
                float dg = (g < n) ? (float)deg[g] : 0.f;
                float val = acc[i][j][r] + b0v + dg * b1v;
                if (do_relu) val = fmaxf(val, 0.f);
                LDS[(mrow + r) * OSTR + nn] = f2bf(val);
            }
        }
    }
    __syncthreads();
    #pragma unroll
    for (int pass = 0; pass < 4; ++pass) {
        int row = pass * 16 + (t >> 4);
        int seg = (t & 15) * 8;
        int g = node0 + row;
        if (g < n)
            *(uint4*)&out[(size_t)g * D + seg] = *(const uint4*)&LDS[row * OSTR + seg];
    }
    if (out32) {
        #pragma unroll
        for (int pass = 0; pass < 8; ++pass) {
            int row = pass * 8 + (t >> 5);
            int seg = (t & 31) * 4;
            int g = node0 + row;
            if (g < n) {
                f32x4 v;
                #pragma unroll
                for (int j = 0; j < 4; ++j) v[j] = bf2f(LDS[row * OSTR + seg + j]);
                *(f32x4*)&out32[(size_t)g * D + seg] = v;
            }
        }
    }
}

// ---------------- last layer (D_out = 3, fp32 out, no relu) ----------------
__global__ void k_last(const unsigned short* __restrict__ z, const unsigned short* __restrict__ sz,
                       const float* __restrict__ W0, const float* __restrict__ b0,
                       const float* __restrict__ W1, const float* __restrict__ b1,
                       const int* __restrict__ deg, float* __restrict__ vert, int n) {
    int t = threadIdx.x;
    int lane = t & 63;
    int node = blockIdx.x * 4 + (t >> 6);
    if (node >= n) return;
    float z0 = bf2f(z[(size_t)node * D + lane]), z1 = bf2f(z[(size_t)node * D + 64 + lane]);
    float s0 = bf2f(sz[(size_t)node * D + lane]), s1 = bf2f(sz[(size_t)node * D + 64 + lane]);
    float dg = (float)deg[node];
    #pragma unroll
    for (int o = 0; o < 3; ++o) {
        float p = z0 * W0[o * D + lane] + z1 * W0[o * D + 64 + lane]
                + s0 * W1[o * D + lane] + s1 * W1[o * D + 64 + lane];
        for (int off = 32; off > 0; off >>= 1) p += __shfl_down(p, off);
        if (lane == 0) vert[(size_t)node * 3 + o] = p + b0[o] + dg * b1[o];
    }
}

extern "C" void kernel_launch(void* const* d_in, const int* in_sizes, int n_in,
                              void* d_out, int out_size, void* d_ws, size_t ws_size,
                              hipStream_t stream) {
    const float* features = (const float*)d_in[0];
    const int*   edges    = (const int*)d_in[1];
    const float* W0_1 = (const float*)d_in[2];
    const float* b0_1 = (const float*)d_in[3];
    const float* W1_1 = (const float*)d_in[4];
    const float* b1_1 = (const float*)d_in[5];
    const float* W0_h = (const float*)d_in[6];
    const float* b0_h = (const float*)d_in[7];
    const float* W1_h = (const float*)d_in[8];
    const float* b1_h = (const float*)d_in[9];
    const float* W0_l = (const float*)d_in[10];
    const float* b0_l = (const float*)d_in[11];
    const float* W1_l = (const float*)d_in[12];
    const float* b1_l = (const float*)d_in[13];

    const int N_ = 100000, E_ = 300000;
    float* vert = (float*)d_out;                    // N*3
    float* aux  = (float*)d_out + (size_t)N_ * 3;   // N*128 fp32

    char* w = (char*)d_ws;
    auto alloc = [&](size_t bytes) {
        char* p = w;
        w += (bytes + 255) & ~(size_t)255;
        return p;
    };
    unsigned short* wb    = (unsigned short*)alloc((size_t)13 * 32768 * 2);
    unsigned short* xf    = (unsigned short*)alloc((size_t)N_ * D * 2);
    unsigned short* resid = (unsigned short*)alloc((size_t)N_ * D * 2);
    unsigned short* xa    = (unsigned short*)alloc((size_t)N_ * D * 2);
    unsigned short* xb    = (unsigned short*)alloc((size_t)N_ * D * 2);
    unsigned short* sb    = (unsigned short*)alloc((size_t)N_ * D * 2);
    int* deg    = (int*)alloc((size_t)N_ * 4);
    int* incl   = (int*)alloc((size_t)N_ * 4);
    int* rowst  = (int*)alloc((size_t)(N_ + 1) * 4);
    int* cursor = (int*)alloc((size_t)N_ * 4);
    int* bsum   = (int*)alloc(128 * 4);
    int* adj    = (int*)alloc((size_t)2 * E_ * 4);

    // CSR build
    hipMemsetAsync(deg, 0, (size_t)N_ * 4, stream);
    k_hist<<<(E_ + 255) / 256, 256, 0, stream>>>(edges, E_, deg);
    int nb = (N_ + 1023) / 1024;   // 98
    k_scan1<<<nb, 1024, 0, stream>>>(deg, N_, incl, bsum);
    k_scan2<<<1, 128, 0, stream>>>(bsum, nb);
    k_scan3<<<(N_ + 255) / 256, 256, 0, stream>>>(incl, deg, bsum, N_, 2 * E_, rowst, cursor);
    k_fill<<<(E_ + 255) / 256, 256, 0, stream>>>(edges, E_, cursor, adj);

    // weight + feature conversion
    k_wprep<<<(13 * 2 * 16384 + 255) / 256, 256, 0, stream>>>(W0_1, W1_1, W0_h, W1_h, wb);
    k_cvt<<<(N_ * D / 4 + 255) / 256, 256, 0, stream>>>(features, xf, N_ * D / 4);

    int gblocks = (N_ + 63) / 64;    // 1563
    int ablocks = (N_ + 15) / 16;    // 6250

    // layer 1: xf -> resid
    k_agg<<<ablocks, 256, 0, stream>>>(xf, rowst, adj, sb, N_);
    k_gemm<<<gblocks, 256, 0, stream>>>(xf, sb, wb, b0_1, b1_1, deg, resid, nullptr, N_, 1);

    // 12 hidden layers
    for (int h = 0; h < 12; ++h) {
        const unsigned short* in = (h == 0) ? resid : ((h & 1) ? xa : xb);
        unsigned short* outp = (h & 1) ? xb : xa;
        float* o32 = (h == 11) ? aux : nullptr;
        k_agg<<<ablocks, 256, 0, stream>>>(in, rowst, adj, sb, N_);
        k_gemm<<<gblocks, 256, 0, stream>>>(in, sb, wb + (size_t)(1 + h) * 32768,
                                            b0_h + h * 128, b1_h + h * 128, deg, outp, o32, N_, 1);
    }

    // last layer: z = resid + x12 (in xb); vertices = gconv(z), no relu
    k_addb<<<(N_ * D / 2 + 255) / 256, 256, 0, stream>>>(resid, xb, xa, N_ * D / 2);
    k_agg<<<ablocks, 256, 0, stream>>>(xa, rowst, adj, sb, N_);
    k_last<<<(N_ + 3) / 4, 256, 0, stream>>>(xa, sb, W0_l, b0_l, W1_l, b1_l, deg, vert, N_);
}